// Round 9
// baseline (223.746 us; speedup 1.0000x reference)
//
#include <hip/hip_runtime.h>
#include <hip/hip_cooperative_groups.h>

namespace cg = cooperative_groups;

// (B,C,H,W) = (4,64,64,64) -> N=4096, Cr=8. Single-head attn, d_k=8, d_v=64.
#define BB 4
#define CC 64
#define NN 4096
#define LOG2E 1.44269504088896340736f

typedef __attribute__((ext_vector_type(8)))  short short8;
typedef __attribute__((ext_vector_type(4)))  short short4v;
typedef __attribute__((ext_vector_type(4)))  float f32x4;
typedef __attribute__((ext_vector_type(16))) float f32x16;
typedef unsigned short u16;

// workspace (all bf16): qws [B*N][8] (pre-scaled by log2e), kws [B*N][8],
// vws [B*64][N] (V transposed, channel-major)
#define QWS_ELEMS (BB * NN * 8)

__device__ inline u16 f2bf(float x) {
    unsigned u = __float_as_uint(x);
    u = (u + 0x7fffu + ((u >> 16) & 1u)) >> 16;   // RNE
    return (u16)u;
}
// truncating bf16 pack of two floats in one v_perm_b32 (P only; 6x error headroom)
__device__ inline unsigned permpack(float lo, float hi) {
    return __builtin_amdgcn_perm(__float_as_uint(hi), __float_as_uint(lo), 0x07060302);
}

// Barrier with LDS-only drain: does NOT wait vmcnt, so global prefetches
// stay in flight across the barrier (LDS ordering is all correctness needs).
__device__ inline void barrier_lgkm() {
    asm volatile("s_waitcnt lgkmcnt(0)\n\ts_barrier" ::: "memory");
}

union SH8 {
    short8 s;
    struct Halves { short4v lo, hi; } h;
    uint4 u;
};

// ---------------------------------------------------------------------------
// Fused cooperative kernel: phase 1 = QKV projection, grid.sync(),
// phase 2 = 32x32x16-MFMA flash attention (R7 structure, exp2 domain).
// Grid 256 x 512 thr = exactly 1 block/CU (co-resident by construction).
// ---------------------------------------------------------------------------
__global__ __launch_bounds__(512) void fused_kernel(
    const float* __restrict__ x,
    const float* __restrict__ wq, const float* __restrict__ bq,
    const float* __restrict__ wk, const float* __restrict__ bk,
    const float* __restrict__ wv, const float* __restrict__ bv,
    const float* __restrict__ gamma,
    u16* __restrict__ ws_u, float* __restrict__ out)
{
    u16* qws = ws_u;
    u16* kws = ws_u + QWS_ELEMS;
    u16* vws = ws_u + 2 * QWS_ELEMS;

    // smem (attn phase): v_t [2][64*132] u16 (33792 B) ALIASED with
    // eb [8][64*17] f32 (34816 B, post-loop only), then l_part, l_inv.
    __shared__ __align__(16) char smem[34816 + 1024 + 256];
    u16*   v_t    = (u16*)smem;
    float* eb     = (float*)smem;
    float* l_part = (float*)(smem + 34816);
    float* l_inv  = (float*)(smem + 34816 + 1024);

    const int tid = threadIdx.x;
    const int blk = blockIdx.x;

    // ---------------- phase 1: projection ----------------
    // block: pg = blk&31 (512 pixels), sl = blk>>5 (10 outs of [q8,k8,v64]).
    {
        const int pg  = blk & 31;
        const int sl  = blk >> 5;
        const int o0  = sl * 10;
        const int pix = (pg << 9) + tid;
        const int b   = pix >> 12;
        const int n   = pix & (NN - 1);
        const float* xb = x + ((size_t)b << 18) + n;

        const float* wrow[10];
        float acc[10];
#pragma unroll
        for (int i = 0; i < 10; ++i) {
            const int o = o0 + i;
            if (o < 8)       { wrow[i] = wq + o * CC;        acc[i] = bq[o]; }
            else if (o < 16) { wrow[i] = wk + (o - 8) * CC;  acc[i] = bk[o - 8]; }
            else             { wrow[i] = wv + (o - 16) * CC; acc[i] = bv[o - 16]; }
        }
#pragma unroll 8
        for (int c = 0; c < CC; ++c) {
            const float xv = xb[(size_t)c << 12];     // coalesced 256B segs
#pragma unroll
            for (int i = 0; i < 10; ++i)
                acc[i] += wrow[i][c] * xv;            // scalar (uniform) loads
        }
#pragma unroll
        for (int i = 0; i < 10; ++i) {
            const int o = o0 + i;
            if (o < 8)                                 // Q pre-scaled by log2e
                qws[(size_t)pix * 8 + o] = f2bf(acc[i] * LOG2E);
            else if (o < 16)
                kws[(size_t)pix * 8 + (o - 8)] = f2bf(acc[i]);
            else
                vws[(((size_t)((b << 6) + (o - 16))) << 12) + n] = f2bf(acc[i]);
        }
    }

    __threadfence();              // release ws writes (cross-XCD)
    cg::this_grid().sync();       // all proj done before any attn reads

    // ---------------- phase 2: attention ----------------
    // blk -> (qb = (blk&63)*64 queries, b = blk>>6 batch). 8 waves =
    // 4 m-chunks x 2 q-halves. 128-key tiles, 32 iters, one lgkm-only
    // barrier per iter. S^T = K*Q^T; exp'd S D-frag repacked IN-REGISTER
    // to the PV A-frag via permuted k-slot order; V B-frags gathered from
    // LDS with the SAME permutation. P never touches LDS.
    {
        const int w    = tid >> 6;
        const int lane = tid & 63;
        const int l31  = lane & 31;
        const int lh   = lane >> 5;
        const int mh   = w >> 1;       // 0..3 m-chunk
        const int qh   = w & 1;        // 0..1 q-half

        const int b  = blk >> 6;
        const int qb = (blk & 63) << 6;
        const int bN = b << 12;

        // S fragments (lanes>=32 supply k-slots 8..15 = zero; 8 real ch)
        short8 qf = {0,0,0,0,0,0,0,0};
        short8 kf = {0,0,0,0,0,0,0,0};
        if (lane < 32) {
            qf = *(const short8*)(qws + (size_t)(bN + qb + (qh << 5) + l31) * 8);
            kf = *(const short8*)(kws + (size_t)(bN + (mh << 5) + l31) * 8);
        }
        short8 kn = kf;

        // V staging: thread -> (row c_st, octets o_st, o_st+64)
        const int c_st = tid >> 3;
        const int o_st = (tid & 7) << 3;
        const u16* vgr = vws + (((size_t)((b << 6) + c_st)) << 12) + o_st;
        const int st0  = c_st * 132 + o_st;              // 132-u16 padded rows

        SH8 va0, va1, vb0, vb1;
        va0.s = *(const short8*)(vgr);                   // tile 0
        va1.s = *(const short8*)(vgr + 64);
        *(short4v*)&v_t[st0]      = va0.h.lo;
        *(short4v*)&v_t[st0 + 4]  = va0.h.hi;
        *(short4v*)&v_t[st0 + 64] = va1.h.lo;
        *(short4v*)&v_t[st0 + 68] = va1.h.hi;
        va0.s = *(const short8*)(vgr + 128);             // tile 1 -> regs
        va1.s = *(const short8*)(vgr + 192);

        // PV read geometry: rows c = l31 / 32+l31; b64 pairs at (mb, mb+8)
        // and (mb+16, mb+24), mb = mh*32 + lh*4 (k-slot permutation).
        const int rA = l31 * 132;
        const int rB = (32 + l31) * 132;
        const int mb = (mh << 5) + (lh << 2);

        f32x16 z16, acc0, acc1;
#pragma unroll
        for (int r = 0; r < 16; ++r) { z16[r] = 0.f; acc0[r] = 0.f; acc1[r] = 0.f; }
        float ls = 0.f;

        barrier_lgkm();   // tile-0 staging visible; tile-1 loads in flight

#pragma unroll 2
        for (int it = 0; it < 32; ++it) {
            const int buf = (it & 1) * 8448;             // CC*132
            const int nxt = ((it + 1) & 31) << 7;        // wrap: warm read
            const int nx2 = ((it + 2) & 31) << 7;

            // top-of-iter global prefetches (consumed next iter; never
            // drained by the lgkm-only barrier)
            vb0.s = *(const short8*)(vgr + nx2);
            vb1.s = *(const short8*)(vgr + nx2 + 64);
            if (lane < 32)
                kn = *(const short8*)(kws + (size_t)(bN + nxt + (mh << 5) + l31) * 8);

            // S^T tile: D[m][q], lane: q=l31, 16 m in regs (log2 domain)
            f32x16 d = __builtin_amdgcn_mfma_f32_32x32x16_bf16(kf, qf, z16, 0, 0, 0);

            float p[16];
#pragma unroll
            for (int r = 0; r < 16; ++r) p[r] = exp2f(d[r]);   // bare v_exp_f32
            float s0 = 0.f, s1 = 0.f;
#pragma unroll
            for (int r = 0; r < 8; ++r) { s0 += p[2 * r]; s1 += p[2 * r + 1]; }
            ls += s0 + s1;

            // in-register D->A repack (slot order = native reg order)
            SH8 A0, A1;
            A0.u.x = permpack(p[0],  p[1]);  A0.u.y = permpack(p[2],  p[3]);
            A0.u.z = permpack(p[4],  p[5]);  A0.u.w = permpack(p[6],  p[7]);
            A1.u.x = permpack(p[8],  p[9]);  A1.u.y = permpack(p[10], p[11]);
            A1.u.z = permpack(p[12], p[13]); A1.u.w = permpack(p[14], p[15]);

            // V B-frags with matching slot permutation (2x b64 each)
            SH8 B00, B01, B10, B11;
            B00.h.lo = *(const short4v*)&v_t[buf + rA + mb];
            B00.h.hi = *(const short4v*)&v_t[buf + rA + mb + 8];
            B01.h.lo = *(const short4v*)&v_t[buf + rB + mb];
            B01.h.hi = *(const short4v*)&v_t[buf + rB + mb + 8];
            B10.h.lo = *(const short4v*)&v_t[buf + rA + mb + 16];
            B10.h.hi = *(const short4v*)&v_t[buf + rA + mb + 24];
            B11.h.lo = *(const short4v*)&v_t[buf + rB + mb + 16];
            B11.h.hi = *(const short4v*)&v_t[buf + rB + mb + 24];

            acc0 = __builtin_amdgcn_mfma_f32_32x32x16_bf16(A0.s, B00.s, acc0, 0, 0, 0);
            acc1 = __builtin_amdgcn_mfma_f32_32x32x16_bf16(A0.s, B01.s, acc1, 0, 0, 0);
            acc0 = __builtin_amdgcn_mfma_f32_32x32x16_bf16(A1.s, B10.s, acc0, 0, 0, 0);
            acc1 = __builtin_amdgcn_mfma_f32_32x32x16_bf16(A1.s, B11.s, acc1, 0, 0, 0);

            // stage tile t+1 into the other buffer
            const int ob = 8448 - buf;
            *(short4v*)&v_t[ob + st0]      = va0.h.lo;
            *(short4v*)&v_t[ob + st0 + 4]  = va0.h.hi;
            *(short4v*)&v_t[ob + st0 + 64] = va1.h.lo;
            *(short4v*)&v_t[ob + st0 + 68] = va1.h.hi;
            va0 = vb0; va1 = vb1;
            kf = kn;

            barrier_lgkm();   // LDS-only drain: prefetches stay in flight
        }

        // softmax denominators: lanes (l, l+32) share q=l31, disjoint m
        float lt = ls + __shfl_xor(ls, 32, 64);
        if (lane < 32) l_part[(mh * 2 + qh) * 32 + l31] = lt;
        __syncthreads();
        if (w < 2 && lane < 32) {
            float s = l_part[(0 * 2 + qh) * 32 + l31] + l_part[(1 * 2 + qh) * 32 + l31]
                    + l_part[(2 * 2 + qh) * 32 + l31] + l_part[(3 * 2 + qh) * 32 + l31];
            l_inv[qh * 32 + l31] = 1.0f / s;
        }

        // tree-reduce acc over the 4 m-chunks (opaque [lane][reg] blobs)
        if (mh >= 2) {
            float* e0 = &eb[(((mh - 2) << 2) + (qh << 1) + 0) * 1088 + lane * 17];
            float* e1 = &eb[(((mh - 2) << 2) + (qh << 1) + 1) * 1088 + lane * 17];
#pragma unroll
            for (int r = 0; r < 16; ++r) { e0[r] = acc0[r]; e1[r] = acc1[r]; }
        }
        __syncthreads();
        if (mh < 2) {
            const float* e0 = &eb[((mh << 2) + (qh << 1) + 0) * 1088 + lane * 17];
            const float* e1 = &eb[((mh << 2) + (qh << 1) + 1) * 1088 + lane * 17];
#pragma unroll
            for (int r = 0; r < 16; ++r) { acc0[r] += e0[r]; acc1[r] += e1[r]; }
        }
        __syncthreads();
        if (mh == 1) {
            float* e0 = &eb[((qh << 1) + 0) * 1088 + lane * 17];
            float* e1 = &eb[((qh << 1) + 1) * 1088 + lane * 17];
#pragma unroll
            for (int r = 0; r < 16; ++r) { e0[r] = acc0[r]; e1[r] = acc1[r]; }
        }
        __syncthreads();
        if (w < 2) {
            const float* e0 = &eb[((qh << 1) + 0) * 1088 + lane * 17];
            const float* e1 = &eb[((qh << 1) + 1) * 1088 + lane * 17];
#pragma unroll
            for (int r = 0; r < 16; ++r) { acc0[r] += e0[r]; acc1[r] += e1[r]; }

            // D rows: q = 8k + 4*lh + (r&3); col c = l31 (+32)
            f32x4 li[4];
#pragma unroll
            for (int k = 0; k < 4; ++k)
                li[k] = *(const f32x4*)&l_inv[qh * 32 + (k << 3) + (lh << 2)];
            const float g = gamma[0];
#pragma unroll
            for (int ch = 0; ch < 2; ++ch) {
                const int c = (ch << 5) + l31;
                const f32x16 a = ch ? acc1 : acc0;
                const size_t rowb = (((size_t)((b << 6) + c)) << 12) + qb + (qh << 5);
#pragma unroll
                for (int k = 0; k < 4; ++k) {
                    const int q0 = (k << 3) + (lh << 2);
                    const float4 xv = *(const float4*)&x[rowb + q0];
                    float4 o;
                    o.x = xv.x + g * a[4 * k + 0] * li[k][0];
                    o.y = xv.y + g * a[4 * k + 1] * li[k][1];
                    o.z = xv.z + g * a[4 * k + 2] * li[k][2];
                    o.w = xv.w + g * a[4 * k + 3] * li[k][3];
                    *(float4*)&out[rowb + q0] = o;
                }
            }
        }
    }
}

// ---------------------------------------------------------------------------
extern "C" void kernel_launch(void* const* d_in, const int* in_sizes, int n_in,
                              void* d_out, int out_size, void* d_ws, size_t ws_size,
                              hipStream_t stream)
{
    const float* x     = (const float*)d_in[0];
    const float* wq    = (const float*)d_in[1];
    const float* bq    = (const float*)d_in[2];
    const float* wk    = (const float*)d_in[3];
    const float* bk    = (const float*)d_in[4];
    const float* wv    = (const float*)d_in[5];
    const float* bv    = (const float*)d_in[6];
    const float* gamma = (const float*)d_in[7];
    u16*   ws  = (u16*)d_ws;
    float* out = (float*)d_out;

    void* args[] = {(void*)&x, (void*)&wq, (void*)&bq, (void*)&wk, (void*)&bk,
                    (void*)&wv, (void*)&bv, (void*)&gamma, (void*)&ws, (void*)&out};
    hipLaunchCooperativeKernel((void*)fused_kernel, dim3(256), dim3(512),
                               args, 0, stream);
}

// Round 10
// 107.806 us; speedup vs baseline: 2.0755x; 2.0755x over previous
//
#include <hip/hip_runtime.h>

// (B,C,H,W) = (4,64,64,64) -> N=4096, Cr=8. Single-head attn, d_k=8, d_v=64.
#define BB 4
#define CC 64
#define NN 4096
#define LOG2E 1.44269504088896340736f

typedef __attribute__((ext_vector_type(8)))  short short8;
typedef __attribute__((ext_vector_type(4)))  short short4v;
typedef __attribute__((ext_vector_type(4)))  float f32x4;
typedef __attribute__((ext_vector_type(16))) float f32x16;
typedef unsigned short u16;

// workspace (all bf16):
//   qws [B*N][8]  (pre-scaled by log2e)
//   kws [B*N][8]
//   vws [B][N/4][64][4]  interleaved: elem (b, m, c) at b*262144 + (m>>2)*256 + c*4 + (m&3)
#define QWS_ELEMS (BB * NN * 8)

__device__ inline u16 f2bf(float x) {
    unsigned u = __float_as_uint(x);
    u = (u + 0x7fffu + ((u >> 16) & 1u)) >> 16;   // RNE
    return (u16)u;
}
__device__ inline unsigned pack2rne(float a, float b) {
    return (unsigned)f2bf(a) | ((unsigned)f2bf(b) << 16);
}
// truncating bf16 pack of two floats in one v_perm_b32 (P only; 6x error headroom)
__device__ inline unsigned permpack(float lo, float hi) {
    return __builtin_amdgcn_perm(__float_as_uint(hi), __float_as_uint(lo), 0x07060302);
}

union SH8 {
    short8 s;
    struct Halves { short4v lo, hi; } h;
    uint4 u;
};

// ---------------------------------------------------------------------------
// Kernel 1: QKV projection (R7 structure). Grid (32, 9) x 512 thr.
// blockIdx.y = block-uniform output slice (-> SGPR weight loads):
// y<8: v[8y..8y+8) stored in the interleaved V layout; y==8: q(+log2e scale), k.
// ---------------------------------------------------------------------------
__global__ __launch_bounds__(512) void proj_kernel(
    const float* __restrict__ x,
    const float* __restrict__ wq, const float* __restrict__ bq,
    const float* __restrict__ wk, const float* __restrict__ bk,
    const float* __restrict__ wv, const float* __restrict__ bv,
    u16* __restrict__ ws_u)
{
    u16* qws = ws_u;
    u16* kws = ws_u + QWS_ELEMS;
    u16* vws = ws_u + 2 * QWS_ELEMS;

    const int y   = blockIdx.y;                    // 0..8, block-uniform
    const int pix = blockIdx.x * 512 + threadIdx.x;
    const int b   = pix >> 12;
    const int n   = pix & (NN - 1);
    const float* xb = x + ((size_t)b << 18) + n;

    if (y < 8) {
        const int v0 = y << 3;
        float av[8];
#pragma unroll
        for (int i = 0; i < 8; ++i) av[i] = bv[v0 + i];
#pragma unroll 8
        for (int c = 0; c < CC; ++c) {
            const float xv = xb[(size_t)c << 12];          // coalesced 256B/wave
#pragma unroll
            for (int i = 0; i < 8; ++i)
                av[i] += wv[(v0 + i) * CC + c] * xv;       // scalar (uniform) loads
        }
        u16* vdst = vws + (size_t)b * 262144 + ((n >> 2) << 8) + (n & 3);
#pragma unroll
        for (int i = 0; i < 8; ++i)
            vdst[(v0 + i) << 2] = f2bf(av[i]);
    } else {
        float aq[8], ak[8];
#pragma unroll
        for (int i = 0; i < 8; ++i) { aq[i] = bq[i]; ak[i] = bk[i]; }
#pragma unroll 8
        for (int c = 0; c < CC; ++c) {
            const float xv = xb[(size_t)c << 12];
#pragma unroll
            for (int i = 0; i < 8; ++i) {
                aq[i] += wq[i * CC + c] * xv;
                ak[i] += wk[i * CC + c] * xv;
            }
        }
        uint4 qp, kp;
        qp.x = pack2rne(aq[0] * LOG2E, aq[1] * LOG2E);
        qp.y = pack2rne(aq[2] * LOG2E, aq[3] * LOG2E);
        qp.z = pack2rne(aq[4] * LOG2E, aq[5] * LOG2E);
        qp.w = pack2rne(aq[6] * LOG2E, aq[7] * LOG2E);
        kp.x = pack2rne(ak[0], ak[1]); kp.y = pack2rne(ak[2], ak[3]);
        kp.z = pack2rne(ak[4], ak[5]); kp.w = pack2rne(ak[6], ak[7]);
        *(uint4*)&qws[(size_t)pix * 8] = qp;               // 16B/lane coalesced
        *(uint4*)&kws[(size_t)pix * 8] = kp;
    }
}

// ---------------------------------------------------------------------------
// Kernel 2: barrier-free MFMA flash attention. Block 256 thr (4 waves =
// 4 m-quarters of one 32-q group), grid (128,4) = 512 blocks = 2/CU.
// NO LDS / NO barrier in the K-loop: V B-fragments are single coalesced
// global b64 loads from the interleaved layout (L2-resident), software-
// pipelined one 32-m tile ahead. S^T = K*Q^T (exp2 domain, Q pre-scaled);
// exp'd S D-frag repacked in-register to the PV A-frag (permuted k-slots,
// matching the V group addressing). Epilogue: 4-wave l/acc reduction (R8).
// ---------------------------------------------------------------------------
__global__ __launch_bounds__(256, 2) void attn_kernel(
    const float* __restrict__ x, const float* __restrict__ gamma,
    const u16* __restrict__ ws_u, float* __restrict__ out)
{
    const u16* qws = ws_u;
    const u16* kws = ws_u + QWS_ELEMS;
    const u16* vws = ws_u + 2 * QWS_ELEMS;

    __shared__ float eb[4 * 1088];     // 17408 B reduction scratch
    __shared__ float l_part[4 * 32];
    __shared__ float l_inv[32];

    const int tid  = threadIdx.x;
    const int w    = tid >> 6;     // 0..3 = m-quarter
    const int lane = tid & 63;
    const int l31  = lane & 31;
    const int lh   = lane >> 5;

    const int b  = blockIdx.y;
    const int qb = blockIdx.x << 5;   // 32 queries/block
    const int bN = b << 12;

    // Q B-frag (lanes>=32 supply k-slots 8..15 = zero; 8 real channels)
    short8 qf = {0,0,0,0,0,0,0,0};
    if (lane < 32)
        qf = *(const short8*)(qws + (size_t)(bN + qb + l31) * 8);

    // K A-frags: wave's m-quarter stream, 32 m/tile, prefetched one ahead
    const u16* kp = kws + (size_t)(bN + (w << 10) + l31) * 8;   // lanes<32 real
    short8 kf = {0,0,0,0,0,0,0,0}, kn = kf;
    if (lane < 32) kf = *(const short8*)kp;
    kp += 32 * 8;

    // V B-frag geometry (interleaved layout): per 2048-elem (32-m) tile
    // window, lane reads b64s at o00 (+512 | +128 | +640 | +1024 | +1536 |
    // +1152 | +1664) covering {k-half0,1} x {c-half0,1} with the k-slot
    // permutation m_local = (j&3) + 8*(j>>2) + 4*lh.
    const u16* vp = vws + (size_t)b * 262144 + (w << 16);   // quarter base
    const int o00 = (lh << 8) + (l31 << 2);

    SH8 C00, C01, C10, C11, N00, N01, N10, N11;
    C00.h.lo = *(const short4v*)(vp + o00);          // tile 0 fragments
    C00.h.hi = *(const short4v*)(vp + o00 + 512);
    C01.h.lo = *(const short4v*)(vp + o00 + 128);
    C01.h.hi = *(const short4v*)(vp + o00 + 640);
    C10.h.lo = *(const short4v*)(vp + o00 + 1024);
    C10.h.hi = *(const short4v*)(vp + o00 + 1536);
    C11.h.lo = *(const short4v*)(vp + o00 + 1152);
    C11.h.hi = *(const short4v*)(vp + o00 + 1664);
    vp += 2048;

    f32x16 z16, acc0, acc1;
#pragma unroll
    for (int r = 0; r < 16; ++r) { z16[r] = 0.f; acc0[r] = 0.f; acc1[r] = 0.f; }
    float ls = 0.f;

    for (int it = 0; it < 32; ++it) {
        // prefetch tile it+1 (final iter reads harmless in-ws garbage, unused)
        N00.h.lo = *(const short4v*)(vp + o00);
        N00.h.hi = *(const short4v*)(vp + o00 + 512);
        N01.h.lo = *(const short4v*)(vp + o00 + 128);
        N01.h.hi = *(const short4v*)(vp + o00 + 640);
        N10.h.lo = *(const short4v*)(vp + o00 + 1024);
        N10.h.hi = *(const short4v*)(vp + o00 + 1536);
        N11.h.lo = *(const short4v*)(vp + o00 + 1152);
        N11.h.hi = *(const short4v*)(vp + o00 + 1664);
        vp += 2048;
        if (lane < 32) kn = *(const short8*)kp;
        kp += 32 * 8;

        // S^T tile: D[m][q], lane: q=l31, 16 m (of this tile) in regs
        f32x16 d = __builtin_amdgcn_mfma_f32_32x32x16_bf16(kf, qf, z16, 0, 0, 0);

        float p[16];
#pragma unroll
        for (int r = 0; r < 16; ++r) p[r] = exp2f(d[r]);   // Q pre-scaled
        float s0 = 0.f, s1 = 0.f;
#pragma unroll
        for (int r = 0; r < 8; ++r) { s0 += p[2 * r]; s1 += p[2 * r + 1]; }
        ls += s0 + s1;

        // in-register D->A repack (slot order = native reg order per lane)
        SH8 A0, A1;
        A0.u.x = permpack(p[0],  p[1]);  A0.u.y = permpack(p[2],  p[3]);
        A0.u.z = permpack(p[4],  p[5]);  A0.u.w = permpack(p[6],  p[7]);
        A1.u.x = permpack(p[8],  p[9]);  A1.u.y = permpack(p[10], p[11]);
        A1.u.z = permpack(p[12], p[13]); A1.u.w = permpack(p[14], p[15]);

        acc0 = __builtin_amdgcn_mfma_f32_32x32x16_bf16(A0.s, C00.s, acc0, 0, 0, 0);
        acc1 = __builtin_amdgcn_mfma_f32_32x32x16_bf16(A0.s, C01.s, acc1, 0, 0, 0);
        acc0 = __builtin_amdgcn_mfma_f32_32x32x16_bf16(A1.s, C10.s, acc0, 0, 0, 0);
        acc1 = __builtin_amdgcn_mfma_f32_32x32x16_bf16(A1.s, C11.s, acc1, 0, 0, 0);

        C00 = N00; C01 = N01; C10 = N10; C11 = N11;
        kf = kn;
    }

    // softmax denominator: lanes (l, l+32) share q=l31, disjoint m
    float lt = ls + __shfl_xor(ls, 32, 64);
    if (lane < 32) l_part[(w << 5) + l31] = lt;
    __syncthreads();
    if (w == 0 && lane < 32)
        l_inv[l31] = 1.0f / (l_part[l31] + l_part[32 + l31] +
                             l_part[64 + l31] + l_part[96 + l31]);

    // tree-reduce acc over the 4 m-quarter waves (opaque [lane][reg] blobs)
    if (w >= 2) {
        float* e0 = &eb[(((w - 2) << 1) + 0) * 1088 + lane * 17];
        float* e1 = &eb[(((w - 2) << 1) + 1) * 1088 + lane * 17];
#pragma unroll
        for (int r = 0; r < 16; ++r) { e0[r] = acc0[r]; e1[r] = acc1[r]; }
    }
    __syncthreads();
    if (w < 2) {
        const float* e0 = &eb[((w << 1) + 0) * 1088 + lane * 17];
        const float* e1 = &eb[((w << 1) + 1) * 1088 + lane * 17];
#pragma unroll
        for (int r = 0; r < 16; ++r) { acc0[r] += e0[r]; acc1[r] += e1[r]; }
    }
    __syncthreads();
    if (w == 1) {
        float* e0 = &eb[0 * 1088 + lane * 17];
        float* e1 = &eb[1 * 1088 + lane * 17];
#pragma unroll
        for (int r = 0; r < 16; ++r) { e0[r] = acc0[r]; e1[r] = acc1[r]; }
    }
    __syncthreads();
    if (w == 0) {
        const float* e0 = &eb[0 * 1088 + lane * 17];
        const float* e1 = &eb[1 * 1088 + lane * 17];
#pragma unroll
        for (int r = 0; r < 16; ++r) { acc0[r] += e0[r]; acc1[r] += e1[r]; }

        // D rows: q = 8k + 4*lh + (r&3) for regs 4k..4k+3; col c = l31 (+32)
        f32x4 li[4];
#pragma unroll
        for (int k = 0; k < 4; ++k)
            li[k] = *(const f32x4*)&l_inv[(k << 3) + (lh << 2)];
        const float g = gamma[0];
#pragma unroll
        for (int ch = 0; ch < 2; ++ch) {
            const int c = (ch << 5) + l31;
            const f32x16 a = ch ? acc1 : acc0;
            const size_t rowb = (((size_t)((b << 6) + c)) << 12) + qb;
#pragma unroll
            for (int k = 0; k < 4; ++k) {
                const int q0 = (k << 3) + (lh << 2);
                const float4 xv = *(const float4*)&x[rowb + q0];
                float4 o;
                o.x = xv.x + g * a[4 * k + 0] * li[k][0];
                o.y = xv.y + g * a[4 * k + 1] * li[k][1];
                o.z = xv.z + g * a[4 * k + 2] * li[k][2];
                o.w = xv.w + g * a[4 * k + 3] * li[k][3];
                *(float4*)&out[rowb + q0] = o;
            }
        }
    }
}

// ---------------------------------------------------------------------------
extern "C" void kernel_launch(void* const* d_in, const int* in_sizes, int n_in,
                              void* d_out, int out_size, void* d_ws, size_t ws_size,
                              hipStream_t stream)
{
    const float* x     = (const float*)d_in[0];
    const float* wq    = (const float*)d_in[1];
    const float* bq    = (const float*)d_in[2];
    const float* wk    = (const float*)d_in[3];
    const float* bk    = (const float*)d_in[4];
    const float* wv    = (const float*)d_in[5];
    const float* bv    = (const float*)d_in[6];
    const float* gamma = (const float*)d_in[7];
    u16*   ws  = (u16*)d_ws;
    float* out = (float*)d_out;

    hipLaunchKernelGGL(proj_kernel, dim3(BB * NN / 512, 9), dim3(512), 0, stream,
                       x, wq, bq, wk, bk, wv, bv, ws);
    hipLaunchKernelGGL(attn_kernel, dim3(NN / 32, BB), dim3(256), 0, stream,
                       x, gamma, ws, out);
}